// Round 3
// baseline (537.939 us; speedup 1.0000x reference)
//
#include <hip/hip_runtime.h>
#include <math.h>

// Problem constants
#define BB   16
#define TT   4
#define CC   2048
#define NH   16
#define NKV  4
#define DH   128
#define GRP  4
#define SCACHE 4096
#define SATT 2052          // sink(4) + window(2048)
#define CS   128           // keys per attention chunk
#define NCH  17            // ceil(2052/128)

typedef unsigned int  uint32;
typedef unsigned short ushort_t;

__device__ __forceinline__ float bf_lo(uint32 u) { return __uint_as_float(u << 16); }
__device__ __forceinline__ float bf_hi(uint32 u) { return __uint_as_float(u & 0xFFFF0000u); }
__device__ __forceinline__ uint32 f2bf_bits(float f) {
    uint32 u = __float_as_uint(f);
    uint32 r = u + 0x7FFFu + ((u >> 16) & 1u);
    return r >> 16;
}

// ---- Workspace layout (bytes) ----
// qws   fp32 [B][NH][T][DH]       @ 0         (524288)
// knew  fp32 [B][NKV][T][DH]      @ 524288    (131072)
// vnew  fp32 [B][NKV][T][DH]      @ 655360    (131072)
// yws   fp32 [64][2048]           @ 786432    (524288)
// SCRATCH @ 1310720, reused sequentially:
//   part_qkv fp32 [4][64][3072]   (3145728)   k_qkv -> k_fix
//   part     fp32 [64*17][16][132](9191424)   k_attn -> k_comb
//   part_p   fp32 [4][64][2048]   (2097152)   k_proj -> k_out
// total 10,502,144 B
#define Q_OFF    0
#define KNEW_OFF 524288
#define VNEW_OFF 655360
#define Y_OFF    786432
#define SCR_OFF  1310720

// -------- Kernel 1: QKV GEMM, K-split partials ---------------------------------
// grid (6 n-slices, 8 m-tiles, 4 k-splits), 256 threads.
// C[64 x 3072] = X[64 x 2048] * [Wq | Wk | Wv]
__global__ __launch_bounds__(256) void k_qkv(
    const float* __restrict__ x, const float* __restrict__ wq,
    const float* __restrict__ wk, const float* __restrict__ wv,
    float* __restrict__ part_qkv)
{
    __shared__ float xs[8][512];
    int ns = blockIdx.x, mt = blockIdx.y, ks = blockIdx.z;
    int tid = threadIdx.x;
    int m0 = mt * 8, k0 = ks * 512;

    // stage X tile [8 m][512 k]
    #pragma unroll
    for (int it = 0; it < 4; ++it) {
        int slot = it * 256 + tid;           // 1024 float4 slots
        int row = slot >> 7, c4 = slot & 127;
        *(float4*)&xs[row][c4 * 4] = *(const float4*)(x + (m0 + row) * CC + k0 + c4 * 4);
    }
    __syncthreads();

    const float* wp; int ldw, col;
    if (ns < 4)      { wp = wq + (size_t)k0 * 2048 + ns * 512 + tid * 2; ldw = 2048; col = ns * 512 + tid * 2; }
    else if (ns == 4){ wp = wk + (size_t)k0 * 512 + tid * 2;             ldw = 512;  col = 2048 + tid * 2; }
    else             { wp = wv + (size_t)k0 * 512 + tid * 2;             ldw = 512;  col = 2560 + tid * 2; }

    float a[16];
    #pragma unroll
    for (int i = 0; i < 16; ++i) a[i] = 0.f;

    for (int k = 0; k < 512; ++k) {
        float2 w = *(const float2*)wp;
        wp += ldw;
        #pragma unroll
        for (int m = 0; m < 8; ++m) {
            float xv = xs[m][k];
            a[2*m]   = fmaf(xv, w.x, a[2*m]);
            a[2*m+1] = fmaf(xv, w.y, a[2*m+1]);
        }
    }
    #pragma unroll
    for (int m = 0; m < 8; ++m) {
        float* dst = part_qkv + ((size_t)(ks * 64 + m0 + m) * 3072) + col;
        *(float2*)dst = make_float2(a[2*m], a[2*m+1]);
    }
}

// -------- Kernel 2: combine K-split partials + RoPE ----------------------------
// grid (6, 64): u = bx.x*256+tid in [0,1536), m = bx.y
__global__ __launch_bounds__(256) void k_fix(
    const float* __restrict__ part_qkv, const int* __restrict__ spp,
    float* __restrict__ qws, float* __restrict__ knew, float* __restrict__ vnew)
{
    int u = blockIdx.x * 256 + threadIdx.x;
    int m = blockIdx.y;
    int b = m >> 2, t = m & 3;
    int sp = spp[0];
    if (sp > 100000000 || sp < 0) sp = (int)__int_as_float(sp);  // dtype guard
    const float NEG_L2_10K_64 = -0.20762050593048633f;

    if (u < 1024) {               // Q rotate pair (d, d+64)
        int h = u >> 6, d = u & 63;
        int col = h * 128 + d;
        float s1 = 0.f, s2 = 0.f;
        #pragma unroll
        for (int ks = 0; ks < 4; ++ks) {
            const float* p = part_qkv + (size_t)(ks * 64 + m) * 3072;
            s1 += p[col]; s2 += p[col + 64];
        }
        float inv = exp2f((float)d * NEG_L2_10K_64);
        float ang = (float)(sp + t) * inv;
        float cc = cosf(ang), ss = sinf(ang);
        float* dst = qws + (size_t)((b * NH + h) * TT + t) * DH + d;
        dst[0]  = s1 * cc - s2 * ss;
        dst[64] = s1 * ss + s2 * cc;
    } else if (u < 1280) {        // K rotate pair
        int v = u - 1024;
        int kv = v >> 6, d = v & 63;
        int col = 2048 + kv * 128 + d;
        float s1 = 0.f, s2 = 0.f;
        #pragma unroll
        for (int ks = 0; ks < 4; ++ks) {
            const float* p = part_qkv + (size_t)(ks * 64 + m) * 3072;
            s1 += p[col]; s2 += p[col + 64];
        }
        float inv = exp2f((float)d * NEG_L2_10K_64);
        float ang = (float)(sp + t) * inv;
        float cc = cosf(ang), ss = sinf(ang);
        float* dst = knew + (size_t)((b * NKV + kv) * TT + t) * DH + d;
        dst[0]  = s1 * cc - s2 * ss;
        dst[64] = s1 * ss + s2 * cc;
    } else {                      // V: plain sum of partials, 2 cols per thread
        int v = u - 1280;         // [0,256)
        int c0 = v * 2;           // within [0,512)
        int kv = c0 >> 7, dd = c0 & 127;
        float s1 = 0.f, s2 = 0.f;
        #pragma unroll
        for (int ks = 0; ks < 4; ++ks) {
            const float* p = part_qkv + (size_t)(ks * 64 + m) * 3072 + 2560 + c0;
            s1 += p[0]; s2 += p[1];
        }
        float* dst = vnew + (size_t)((b * NKV + kv) * TT + t) * DH + dd;
        dst[0] = s1; dst[1] = s2;
    }
}

// key/value row j in [0, 2052)
__device__ __forceinline__ const float* kv_row(
    const float* cache, const float* newt, int bk, int j)
{
    if (j < 4)         return cache + ((size_t)bk * SCACHE + j) * DH;
    else if (j < 2048) return cache + ((size_t)bk * SCACHE + j + 2048) * DH;
    else               return newt  + ((size_t)(bk * TT + (j - 2048))) * DH;
}

// -------- Kernel 3: split-S attention partials ---------------------------------
// grid 64*17. One WG per (b,kvh,chunk of 128 keys). 16 query rows.
// K tile staged in LDS as packed bf16 (lossless: values are bf16-precision).
__global__ __launch_bounds__(256) void k_attn(
    const float* __restrict__ qws,
    const float* __restrict__ kc, const float* __restrict__ vc,
    const float* __restrict__ knew, const float* __restrict__ vnew,
    float* __restrict__ part)
{
    __shared__ float  q_s[16][132];
    __shared__ uint32 k_s[CS][66];
    __shared__ float  s_s[16][CS + 2];
    __shared__ float  red_s[16][16];

    int bx = blockIdx.x;
    int c  = bx % NCH;
    int bk = bx / NCH;                 // b*NKV + kvh
    int b  = bk >> 2, kvh = bk & 3;
    int j0 = c * CS;
    int jn = (SATT - j0 < CS) ? (SATT - j0) : CS;
    int tid = threadIdx.x;

    // stage Q tile [16][128]
    for (int i = tid; i < 16 * 128; i += 256) {
        int rr = i >> 7, d = i & 127;
        int h = kvh * GRP + (rr >> 2), t = rr & 3;
        q_s[rr][d] = qws[(size_t)((b * NH + h) * TT + t) * DH + d];
    }
    // stage K tile [128 rows][64 uint32 = 128 bf16], zero-pad beyond jn
    #pragma unroll
    for (int it = 0; it < 32; ++it) {
        int slot = it * 256 + tid;     // 8192 slots
        int row = slot >> 6, c2 = slot & 63;
        uint32 val = 0;
        if (row < jn) {
            const float* kr = kv_row(kc, knew, bk, j0 + row);
            float2 f = *(const float2*)(kr + c2 * 2);
            val = f2bf_bits(f.x) | (f2bf_bits(f.y) << 16);
        }
        k_s[row][c2] = val;
    }
    __syncthreads();

    int r  = tid >> 4;                 // query row 0..15
    int kt = tid & 15;
    const float scale = 0.08838834764831845f;

    // scores: thread (r,kt) computes rows r, keys kl = kt+16*jj
    #pragma unroll
    for (int jj = 0; jj < CS / 16; ++jj) {
        int kl = kt + 16 * jj;
        float a = 0.f;
        #pragma unroll 8
        for (int c2 = 0; c2 < 64; ++c2) {
            uint32 u = k_s[kl][c2];
            float2 q2 = *(const float2*)&q_s[r][c2 * 2];
            a = fmaf(q2.x, bf_lo(u), a);
            a = fmaf(q2.y, bf_hi(u), a);
        }
        s_s[r][kl] = (kl < jn) ? a * scale : -1e30f;
    }
    // row max
    float locmax = -1e30f;
    #pragma unroll
    for (int jj = 0; jj < CS / 16; ++jj) locmax = fmaxf(locmax, s_s[r][kt + 16 * jj]);
    red_s[r][kt] = locmax;
    __syncthreads();
    float mn = red_s[r][0];
    #pragma unroll
    for (int i = 1; i < 16; ++i) mn = fmaxf(mn, red_s[r][i]);
    // p = exp(s-mn), partial sums
    float psum = 0.f;
    #pragma unroll
    for (int jj = 0; jj < CS / 16; ++jj) {
        int kl = kt + 16 * jj;
        float p = expf(s_s[r][kl] - mn);    // padded: exp(-1e30)=0
        s_s[r][kl] = p;
        psum += p;
    }
    __syncthreads();                        // s_s writes done before PV reads
    red_s[r][kt] = psum;
    __syncthreads();
    float lsum = 0.f;
    #pragma unroll
    for (int i = 0; i < 16; ++i) lsum += red_s[r][i];

    // PV: thread (r,kt) accumulates d in [kt*8, kt*8+8) of row r
    int d8 = kt * 8;
    float a0=0,a1=0,a2=0,a3=0,a4=0,a5=0,a6=0,a7=0;
    for (int kl = 0; kl < jn; ++kl) {
        float p = s_s[r][kl];
        const float* vr = kv_row(vc, vnew, bk, j0 + kl) + d8;
        float4 u0 = *(const float4*)vr;
        float4 u1 = *(const float4*)(vr + 4);
        a0 = fmaf(p, u0.x, a0); a1 = fmaf(p, u0.y, a1);
        a2 = fmaf(p, u0.z, a2); a3 = fmaf(p, u0.w, a3);
        a4 = fmaf(p, u1.x, a4); a5 = fmaf(p, u1.y, a5);
        a6 = fmaf(p, u1.z, a6); a7 = fmaf(p, u1.w, a7);
    }
    float* dst = part + ((size_t)(bk * NCH + c) * 16 + r) * 132;
    if (kt == 0) { dst[0] = mn; dst[1] = lsum; }
    *(float4*)(dst + 4 + d8)     = make_float4(a0, a1, a2, a3);
    *(float4*)(dst + 4 + d8 + 4) = make_float4(a4, a5, a6, a7);
}

// -------- Kernel 4: combine chunk partials -> yws ------------------------------
__global__ __launch_bounds__(128) void k_comb(
    const float* __restrict__ part, float* __restrict__ yws)
{
    int bx = blockIdx.x;               // 1024 = B*NH*T
    int t = bx & 3, h = (bx >> 2) & 15, b = bx >> 6;
    int bk = b * NKV + (h >> 2);
    int r  = (h & 3) * 4 + t;
    int d  = threadIdx.x;
    float M = -1e30f;
    for (int c = 0; c < NCH; ++c)
        M = fmaxf(M, part[((size_t)(bk * NCH + c) * 16 + r) * 132]);
    float L = 0.f, y = 0.f;
    for (int c = 0; c < NCH; ++c) {
        const float* pp = part + ((size_t)(bk * NCH + c) * 16 + r) * 132;
        float w = expf(pp[0] - M);
        L += w * pp[1];
        y  = fmaf(w, pp[4 + d], y);
    }
    yws[(size_t)(b * TT + t) * CC + h * DH + d] = y / L;
}

// -------- Kernel 5: output projection GEMM, K-split partials -------------------
// grid (4 n-slices, 8 m-tiles, 4 k-splits)
__global__ __launch_bounds__(256) void k_proj(
    const float* __restrict__ yws, const float* __restrict__ wp,
    float* __restrict__ part_p)
{
    __shared__ float xs[8][512];
    int ns = blockIdx.x, mt = blockIdx.y, ks = blockIdx.z;
    int tid = threadIdx.x;
    int m0 = mt * 8, k0 = ks * 512;
    #pragma unroll
    for (int it = 0; it < 4; ++it) {
        int slot = it * 256 + tid;
        int row = slot >> 7, c4 = slot & 127;
        *(float4*)&xs[row][c4 * 4] = *(const float4*)(yws + (size_t)(m0 + row) * CC + k0 + c4 * 4);
    }
    __syncthreads();
    int n = ns * 512 + tid * 2;
    const float* w = wp + (size_t)k0 * CC + n;
    float a[16];
    #pragma unroll
    for (int i = 0; i < 16; ++i) a[i] = 0.f;
    for (int k = 0; k < 512; ++k) {
        float2 wv2 = *(const float2*)w;
        w += CC;
        #pragma unroll
        for (int m = 0; m < 8; ++m) {
            float xv = xs[m][k];
            a[2*m]   = fmaf(xv, wv2.x, a[2*m]);
            a[2*m+1] = fmaf(xv, wv2.y, a[2*m+1]);
        }
    }
    #pragma unroll
    for (int m = 0; m < 8; ++m)
        *(float2*)(part_p + ((size_t)(ks * 64 + m0 + m) * CC) + n) = make_float2(a[2*m], a[2*m+1]);
}

// -------- Kernel 6: sum proj partials -> out (fp32) ----------------------------
__global__ __launch_bounds__(256) void k_out(
    const float* __restrict__ part_p, float* __restrict__ out)
{
    int gt = blockIdx.x * 256 + threadIdx.x;   // 131072
    float s = 0.f;
    #pragma unroll
    for (int ks = 0; ks < 4; ++ks) s += part_p[(size_t)ks * 64 * CC + gt];
    out[gt] = s;
}

extern "C" void kernel_launch(void* const* d_in, const int* in_sizes, int n_in,
                              void* d_out, int out_size, void* d_ws, size_t ws_size,
                              hipStream_t stream)
{
    const float* x   = (const float*)d_in[0];
    const float* ck  = (const float*)d_in[1];
    const float* cv  = (const float*)d_in[2];
    const float* wq  = (const float*)d_in[3];
    const float* wk  = (const float*)d_in[4];
    const float* wv  = (const float*)d_in[5];
    const float* wpj = (const float*)d_in[6];
    const int*   sp  = (const int*)d_in[7];
    char* ws = (char*)d_ws;
    float* qws  = (float*)(ws + Q_OFF);
    float* knew = (float*)(ws + KNEW_OFF);
    float* vnew = (float*)(ws + VNEW_OFF);
    float* yws  = (float*)(ws + Y_OFF);
    float* scr  = (float*)(ws + SCR_OFF);      // part_qkv, then part, then part_p
    float* out  = (float*)d_out;

    hipLaunchKernelGGL(k_qkv,  dim3(6, 8, 4), dim3(256), 0, stream, x, wq, wk, wv, scr);
    hipLaunchKernelGGL(k_fix,  dim3(6, 64),   dim3(256), 0, stream, scr, sp, qws, knew, vnew);
    hipLaunchKernelGGL(k_attn, dim3(64 * NCH), dim3(256), 0, stream, qws, ck, cv, knew, vnew, scr);
    hipLaunchKernelGGL(k_comb, dim3(1024),    dim3(128), 0, stream, scr, yws);
    hipLaunchKernelGGL(k_proj, dim3(4, 8, 4), dim3(256), 0, stream, yws, wpj, scr);
    hipLaunchKernelGGL(k_out,  dim3(512),     dim3(256), 0, stream, scr, out);
}

// Round 4
// 467.087 us; speedup vs baseline: 1.1517x; 1.1517x over previous
//
#include <hip/hip_runtime.h>
#include <math.h>

// Problem constants
#define BB   16
#define TT   4
#define CC   2048
#define NH   16
#define NKV  4
#define DH   128
#define GRP  4
#define SCACHE 4096
#define SATT 2052          // sink(4) + window(2048)
#define CS   128           // keys per attention chunk
#define NCH  17            // ceil(2052/128)

typedef unsigned int  uint32;
typedef unsigned short ushort_t;
typedef __attribute__((ext_vector_type(8))) __bf16 bf16x8;
typedef __attribute__((ext_vector_type(4))) float  f32x4;

__device__ __forceinline__ uint32 f2bf_bits(float f) {
    uint32 u = __float_as_uint(f);
    return (u + 0x7FFFu + ((u >> 16) & 1u)) >> 16;   // RN-even
}
__device__ __forceinline__ uint32 pk2(float lo, float hi) {
    return f2bf_bits(lo) | (f2bf_bits(hi) << 16);
}

// ---- Workspace layout (bytes) ---- (same footprint as round 3: 10.5 MB, known-safe)
#define Q_OFF    0
#define KNEW_OFF 524288
#define VNEW_OFF 655360
#define Y_OFF    786432
#define SCR_OFF  1310720

// -------- Kernel 1: QKV GEMM, K-split partials (VALU, 4-row ILP batch) ---------
__global__ __launch_bounds__(256) void k_qkv(
    const float* __restrict__ x, const float* __restrict__ wq,
    const float* __restrict__ wk, const float* __restrict__ wv,
    float* __restrict__ part_qkv)
{
    __shared__ float xs[8][512];
    int ns = blockIdx.x, mt = blockIdx.y, ks = blockIdx.z;
    int tid = threadIdx.x;
    int m0 = mt * 8, k0 = ks * 512;

    #pragma unroll
    for (int it = 0; it < 4; ++it) {
        int slot = it * 256 + tid;
        int row = slot >> 7, c4 = slot & 127;
        *(float4*)&xs[row][c4 * 4] = *(const float4*)(x + (m0 + row) * CC + k0 + c4 * 4);
    }
    __syncthreads();

    const float* wp; int ldw, col;
    if (ns < 4)      { wp = wq + (size_t)k0 * 2048 + ns * 512 + tid * 2; ldw = 2048; col = ns * 512 + tid * 2; }
    else if (ns == 4){ wp = wk + (size_t)k0 * 512 + tid * 2;             ldw = 512;  col = 2048 + tid * 2; }
    else             { wp = wv + (size_t)k0 * 512 + tid * 2;             ldw = 512;  col = 2560 + tid * 2; }

    float a[16];
    #pragma unroll
    for (int i = 0; i < 16; ++i) a[i] = 0.f;

    for (int k = 0; k < 512; k += 4) {
        float2 w0 = *(const float2*)(wp);
        float2 w1 = *(const float2*)(wp + ldw);
        float2 w2 = *(const float2*)(wp + 2 * ldw);
        float2 w3 = *(const float2*)(wp + 3 * ldw);
        wp += 4 * ldw;
        #pragma unroll
        for (int m = 0; m < 8; ++m) {
            float4 xv = *(const float4*)&xs[m][k];
            float s0 = a[2*m], s1 = a[2*m+1];
            s0 = fmaf(xv.x, w0.x, s0); s1 = fmaf(xv.x, w0.y, s1);
            s0 = fmaf(xv.y, w1.x, s0); s1 = fmaf(xv.y, w1.y, s1);
            s0 = fmaf(xv.z, w2.x, s0); s1 = fmaf(xv.z, w2.y, s1);
            s0 = fmaf(xv.w, w3.x, s0); s1 = fmaf(xv.w, w3.y, s1);
            a[2*m] = s0; a[2*m+1] = s1;
        }
    }
    #pragma unroll
    for (int m = 0; m < 8; ++m)
        *(float2*)(part_qkv + ((size_t)(ks * 64 + m0 + m) * 3072) + col) = make_float2(a[2*m], a[2*m+1]);
}

// -------- Kernel 2: combine K-split partials + RoPE (unchanged) ----------------
__global__ __launch_bounds__(256) void k_fix(
    const float* __restrict__ part_qkv, const int* __restrict__ spp,
    float* __restrict__ qws, float* __restrict__ knew, float* __restrict__ vnew)
{
    int u = blockIdx.x * 256 + threadIdx.x;
    int m = blockIdx.y;
    int b = m >> 2, t = m & 3;
    int sp = spp[0];
    const float NEG_L2_10K_64 = -0.20762050593048633f;

    if (u < 1024) {
        int h = u >> 6, d = u & 63;
        int col = h * 128 + d;
        float s1 = 0.f, s2 = 0.f;
        #pragma unroll
        for (int ks = 0; ks < 4; ++ks) {
            const float* p = part_qkv + (size_t)(ks * 64 + m) * 3072;
            s1 += p[col]; s2 += p[col + 64];
        }
        float inv = exp2f((float)d * NEG_L2_10K_64);
        float ang = (float)(sp + t) * inv;
        float cc = cosf(ang), ss = sinf(ang);
        float* dst = qws + (size_t)((b * NH + h) * TT + t) * DH + d;
        dst[0]  = s1 * cc - s2 * ss;
        dst[64] = s1 * ss + s2 * cc;
    } else if (u < 1280) {
        int v = u - 1024;
        int kv = v >> 6, d = v & 63;
        int col = 2048 + kv * 128 + d;
        float s1 = 0.f, s2 = 0.f;
        #pragma unroll
        for (int ks = 0; ks < 4; ++ks) {
            const float* p = part_qkv + (size_t)(ks * 64 + m) * 3072;
            s1 += p[col]; s2 += p[col + 64];
        }
        float inv = exp2f((float)d * NEG_L2_10K_64);
        float ang = (float)(sp + t) * inv;
        float cc = cosf(ang), ss = sinf(ang);
        float* dst = knew + (size_t)((b * NKV + kv) * TT + t) * DH + d;
        dst[0]  = s1 * cc - s2 * ss;
        dst[64] = s1 * ss + s2 * cc;
    } else {
        int v = u - 1280;
        int c0 = v * 2;
        int kv = c0 >> 7, dd = c0 & 127;
        float s1 = 0.f, s2 = 0.f;
        #pragma unroll
        for (int ks = 0; ks < 4; ++ks) {
            const float* p = part_qkv + (size_t)(ks * 64 + m) * 3072 + 2560 + c0;
            s1 += p[0]; s2 += p[1];
        }
        float* dst = vnew + (size_t)((b * NKV + kv) * TT + t) * DH + dd;
        dst[0] = s1; dst[1] = s2;
    }
}

// key/value row j in [0, 2052)
__device__ __forceinline__ const float* kv_row(
    const float* cache, const float* newt, int bk, int j)
{
    if (j < 4)         return cache + ((size_t)bk * SCACHE + j) * DH;
    else if (j < 2048) return cache + ((size_t)bk * SCACHE + j + 2048) * DH;
    else               return newt  + ((size_t)(bk * TT + (j - 2048))) * DH;
}

// -------- Kernel 3: MFMA flash-decode attention partials -----------------------
// One WG (4 waves) per (b,kvh,chunk of 128 keys). QK^T and PV via
// mfma_f32_16x16x32_bf16. K and transposed-V share one LDS buffer
// (lifetimes disjoint). Verified layouts: A[m=lane&15][k=quad*8+j],
// B[k=quad*8+j][n=lane&15], C/D[row=quad*4+reg][col=lane&15].
__global__ __launch_bounds__(256) void k_attn(
    const float* __restrict__ qws,
    const float* __restrict__ kc, const float* __restrict__ vc,
    const float* __restrict__ knew, const float* __restrict__ vnew,
    float* __restrict__ part)
{
    __shared__ ushort_t kv_lds[128 * 136];   // K rows, then V^T rows (stride 136)
    __shared__ ushort_t p_lds[16 * 136];     // P in bf16, A-layout
    __shared__ float    s_f[16 * 132];       // raw scores fp32
    __shared__ float    red_a[256];
    __shared__ float    red_b[256];

    int bx = blockIdx.x;
    int c  = bx % NCH;
    int bk = bx / NCH;
    int b  = bk >> 2, kvh = bk & 3;
    int j0 = c * CS;
    int jn = (SATT - j0 < CS) ? (SATT - j0) : CS;
    int tid  = threadIdx.x;
    int wave = tid >> 6, lane = tid & 63;
    int quad = lane >> 4, l15 = lane & 15;
    const float scale = 0.08838834764831845f;   // 1/sqrt(128)

    // ---- Q fragments straight to registers (same for all waves) ----
    bf16x8 aq[4];
    {
        int h = kvh * GRP + (l15 >> 2), t = l15 & 3;
        const float* qr = qws + (size_t)((b * NH + h) * TT + t) * DH;
        #pragma unroll
        for (int ks = 0; ks < 4; ++ks) {
            const float* s = qr + ks * 32 + quad * 8;
            float4 f0 = *(const float4*)s;
            float4 f1 = *(const float4*)(s + 4);
            union { uint32 u[4]; bf16x8 v; } pk;
            pk.u[0] = pk2(f0.x, f0.y); pk.u[1] = pk2(f0.z, f0.w);
            pk.u[2] = pk2(f1.x, f1.y); pk.u[3] = pk2(f1.z, f1.w);
            aq[ks] = pk.v;
        }
    }

    // ---- stage K tile [128 rows][128 d] -> bf16 LDS (zero-pad rows >= jn) ----
    #pragma unroll
    for (int it = 0; it < 8; ++it) {
        int slot = it * 256 + tid;          // 2048 slots of 8 elems
        int row = slot >> 4, d0 = (slot & 15) * 8;
        union { uint32 u[4]; bf16x8 v; } pk;
        pk.u[0] = pk.u[1] = pk.u[2] = pk.u[3] = 0;
        if (row < jn) {
            const float* kr = kv_row(kc, knew, bk, j0 + row) + d0;
            float4 f0 = *(const float4*)kr;
            float4 f1 = *(const float4*)(kr + 4);
            pk.u[0] = pk2(f0.x, f0.y); pk.u[1] = pk2(f0.z, f0.w);
            pk.u[2] = pk2(f1.x, f1.y); pk.u[3] = pk2(f1.z, f1.w);
        }
        *(bf16x8*)&kv_lds[row * 136 + d0] = pk.v;
    }
    __syncthreads();

    // ---- QK^T: wave handles key-cols [wave*32, wave*32+32) ----
    int n0 = wave * 32;
    f32x4 s0 = {0.f, 0.f, 0.f, 0.f}, s1 = {0.f, 0.f, 0.f, 0.f};
    #pragma unroll
    for (int ks = 0; ks < 4; ++ks) {
        bf16x8 b0 = *(const bf16x8*)&kv_lds[(n0 + l15) * 136 + ks * 32 + quad * 8];
        bf16x8 b1 = *(const bf16x8*)&kv_lds[(n0 + 16 + l15) * 136 + ks * 32 + quad * 8];
        s0 = __builtin_amdgcn_mfma_f32_16x16x32_bf16(aq[ks], b0, s0, 0, 0, 0);
        s1 = __builtin_amdgcn_mfma_f32_16x16x32_bf16(aq[ks], b1, s1, 0, 0, 0);
    }
    #pragma unroll
    for (int i = 0; i < 4; ++i) {
        s_f[(quad * 4 + i) * 132 + n0 + l15]      = s0[i] * scale;
        s_f[(quad * 4 + i) * 132 + n0 + 16 + l15] = s1[i] * scale;
    }
    __syncthreads();   // K reads done; s_f complete

    // ---- stage V^T into kv_lds: Vt[d][key], pair-packed writes ----
    {
        int dgrp = tid >> 6;                 // 0..3 -> d block of 32
        int kp   = tid & 63;                 // key pair
        int key0 = 2 * kp;
        uint32* vt32 = (uint32*)kv_lds;
        #pragma unroll
        for (int i = 0; i < 8; ++i) {
            int d = dgrp * 32 + i * 4;
            float4 va = make_float4(0.f, 0.f, 0.f, 0.f);
            float4 vb = make_float4(0.f, 0.f, 0.f, 0.f);
            if (key0 < jn)     va = *(const float4*)(kv_row(vc, vnew, bk, j0 + key0) + d);
            if (key0 + 1 < jn) vb = *(const float4*)(kv_row(vc, vnew, bk, j0 + key0 + 1) + d);
            vt32[(d + 0) * 68 + kp] = pk2(va.x, vb.x);
            vt32[(d + 1) * 68 + kp] = pk2(va.y, vb.y);
            vt32[(d + 2) * 68 + kp] = pk2(va.z, vb.z);
            vt32[(d + 3) * 68 + kp] = pk2(va.w, vb.w);
        }
    }

    // ---- softmax (fp32), P -> bf16 A-layout in p_lds ----
    {
        int r = tid >> 4, kt = tid & 15;
        float loc[8];
        float mx = -1e30f;
        #pragma unroll
        for (int jj = 0; jj < 8; ++jj) {
            int kl = kt + 16 * jj;
            float sv = (kl < jn) ? s_f[r * 132 + kl] : -1e30f;
            loc[jj] = sv;
            mx = fmaxf(mx, sv);
        }
        red_a[r * 16 + kt] = mx;
        __syncthreads();
        float mn = red_a[r * 16];
        #pragma unroll
        for (int i = 1; i < 16; ++i) mn = fmaxf(mn, red_a[r * 16 + i]);
        float ps = 0.f;
        #pragma unroll
        for (int jj = 0; jj < 8; ++jj) {
            int kl = kt + 16 * jj;
            float p = __expf(loc[jj] - mn);
            p_lds[r * 136 + kl] = (ushort_t)f2bf_bits(p);
            ps += p;
        }
        red_b[r * 16 + kt] = ps;
        __syncthreads();   // also guards: Vt writes + p_lds writes all done
        if (kt == 0) {
            float ls = 0.f;
            #pragma unroll
            for (int i = 0; i < 16; ++i) ls += red_b[r * 16 + i];
            float* rp = part + ((size_t)(bk * NCH + c) * 16 + r) * 132;
            rp[0] = mn; rp[1] = ls;
        }
    }

    // ---- PV: wave handles d-cols [wave*32, wave*32+32) ----
    int d0 = wave * 32;
    f32x4 o0 = {0.f, 0.f, 0.f, 0.f}, o1 = {0.f, 0.f, 0.f, 0.f};
    #pragma unroll
    for (int ks = 0; ks < 4; ++ks) {
        bf16x8 ap = *(const bf16x8*)&p_lds[l15 * 136 + ks * 32 + quad * 8];
        bf16x8 b0 = *(const bf16x8*)&kv_lds[(d0 + l15) * 136 + ks * 32 + quad * 8];
        bf16x8 b1 = *(const bf16x8*)&kv_lds[(d0 + 16 + l15) * 136 + ks * 32 + quad * 8];
        o0 = __builtin_amdgcn_mfma_f32_16x16x32_bf16(ap, b0, o0, 0, 0, 0);
        o1 = __builtin_amdgcn_mfma_f32_16x16x32_bf16(ap, b1, o1, 0, 0, 0);
    }
    float* dstb = part + (size_t)(bk * NCH + c) * 16 * 132;
    #pragma unroll
    for (int i = 0; i < 4; ++i) {
        int row = quad * 4 + i;
        dstb[row * 132 + 4 + d0 + l15]      = o0[i];
        dstb[row * 132 + 4 + d0 + 16 + l15] = o1[i];
    }
}

// -------- Kernel 4: combine chunk partials -> yws (unchanged) ------------------
__global__ __launch_bounds__(128) void k_comb(
    const float* __restrict__ part, float* __restrict__ yws)
{
    int bx = blockIdx.x;
    int t = bx & 3, h = (bx >> 2) & 15, b = bx >> 6;
    int bk = b * NKV + (h >> 2);
    int r  = (h & 3) * 4 + t;
    int d  = threadIdx.x;
    float M = -1e30f;
    for (int c = 0; c < NCH; ++c)
        M = fmaxf(M, part[((size_t)(bk * NCH + c) * 16 + r) * 132]);
    float L = 0.f, y = 0.f;
    for (int c = 0; c < NCH; ++c) {
        const float* pp = part + ((size_t)(bk * NCH + c) * 16 + r) * 132;
        float w = __expf(pp[0] - M);
        L += w * pp[1];
        y  = fmaf(w, pp[4 + d], y);
    }
    yws[(size_t)(b * TT + t) * CC + h * DH + d] = y / L;
}

// -------- Kernel 5: output projection GEMM (VALU, 4-row ILP batch) -------------
__global__ __launch_bounds__(256) void k_proj(
    const float* __restrict__ yws, const float* __restrict__ wp,
    float* __restrict__ part_p)
{
    __shared__ float xs[8][512];
    int ns = blockIdx.x, mt = blockIdx.y, ks = blockIdx.z;
    int tid = threadIdx.x;
    int m0 = mt * 8, k0 = ks * 512;
    #pragma unroll
    for (int it = 0; it < 4; ++it) {
        int slot = it * 256 + tid;
        int row = slot >> 7, c4 = slot & 127;
        *(float4*)&xs[row][c4 * 4] = *(const float4*)(yws + (size_t)(m0 + row) * CC + k0 + c4 * 4);
    }
    __syncthreads();
    int n = ns * 512 + tid * 2;
    const float* w = wp + (size_t)k0 * CC + n;
    float a[16];
    #pragma unroll
    for (int i = 0; i < 16; ++i) a[i] = 0.f;
    for (int k = 0; k < 512; k += 4) {
        float2 w0 = *(const float2*)(w);
        float2 w1 = *(const float2*)(w + CC);
        float2 w2 = *(const float2*)(w + 2 * CC);
        float2 w3 = *(const float2*)(w + 3 * CC);
        w += 4 * CC;
        #pragma unroll
        for (int m = 0; m < 8; ++m) {
            float4 xv = *(const float4*)&xs[m][k];
            float s0 = a[2*m], s1 = a[2*m+1];
            s0 = fmaf(xv.x, w0.x, s0); s1 = fmaf(xv.x, w0.y, s1);
            s0 = fmaf(xv.y, w1.x, s0); s1 = fmaf(xv.y, w1.y, s1);
            s0 = fmaf(xv.z, w2.x, s0); s1 = fmaf(xv.z, w2.y, s1);
            s0 = fmaf(xv.w, w3.x, s0); s1 = fmaf(xv.w, w3.y, s1);
            a[2*m] = s0; a[2*m+1] = s1;
        }
    }
    #pragma unroll
    for (int m = 0; m < 8; ++m)
        *(float2*)(part_p + ((size_t)(ks * 64 + m0 + m) * CC) + n) = make_float2(a[2*m], a[2*m+1]);
}

// -------- Kernel 6: sum proj partials -> out (unchanged) -----------------------
__global__ __launch_bounds__(256) void k_out(
    const float* __restrict__ part_p, float* __restrict__ out)
{
    int gt = blockIdx.x * 256 + threadIdx.x;
    float s = 0.f;
    #pragma unroll
    for (int ks = 0; ks < 4; ++ks) s += part_p[(size_t)ks * 64 * CC + gt];
    out[gt] = s;
}

extern "C" void kernel_launch(void* const* d_in, const int* in_sizes, int n_in,
                              void* d_out, int out_size, void* d_ws, size_t ws_size,
                              hipStream_t stream)
{
    const float* x   = (const float*)d_in[0];
    const float* ck  = (const float*)d_in[1];
    const float* cv  = (const float*)d_in[2];
    const float* wq  = (const float*)d_in[3];
    const float* wk  = (const float*)d_in[4];
    const float* wv  = (const float*)d_in[5];
    const float* wpj = (const float*)d_in[6];
    const int*   sp  = (const int*)d_in[7];
    char* ws = (char*)d_ws;
    float* qws  = (float*)(ws + Q_OFF);
    float* knew = (float*)(ws + KNEW_OFF);
    float* vnew = (float*)(ws + VNEW_OFF);
    float* yws  = (float*)(ws + Y_OFF);
    float* scr  = (float*)(ws + SCR_OFF);
    float* out  = (float*)d_out;

    hipLaunchKernelGGL(k_qkv,  dim3(6, 8, 4), dim3(256), 0, stream, x, wq, wk, wv, scr);
    hipLaunchKernelGGL(k_fix,  dim3(6, 64),   dim3(256), 0, stream, scr, sp, qws, knew, vnew);
    hipLaunchKernelGGL(k_attn, dim3(64 * NCH), dim3(256), 0, stream, qws, ck, cv, knew, vnew, scr);
    hipLaunchKernelGGL(k_comb, dim3(1024),    dim3(128), 0, stream, scr, yws);
    hipLaunchKernelGGL(k_proj, dim3(4, 8, 4), dim3(256), 0, stream, yws, wpj, scr);
    hipLaunchKernelGGL(k_out,  dim3(512),     dim3(256), 0, stream, scr, out);
}